// Round 1
// 942.352 us; speedup vs baseline: 1.2619x; 1.2619x over previous
//
#include <hip/hip_runtime.h>

// Blur (stylegan2 upfirdn2d, up=1, down=1, pad=(1,1)) on (4,128,513,513) f32.
// Output (4,128,512,512). Kernel is rank-1 -> separable 4-tap H + 4-tap V.
//
// v2: no LDS. Baseline was VMEM-instruction-issue bound (281M 4B-wide mem
// insts ~= 1.27 cy/inst/CU). Each thread now owns an 8-col x 32-row output
// tile and slides a 4-row register window down it:
//   per input row: 1 scalar + 2x dwordx4 + 1x dwordx2 loads (11-float window)
//   per output row: 24 FMA vertical + 2 aligned dwordx4 stores
// => ~107M VMEM insts total (2.6x fewer), wide where possible.

#define W_IN  513
#define H_IN  513
#define W_OUT 512
#define H_OUT 512
#define IN_PLANE  (W_IN * H_IN)    // 263169
#define OUT_PLANE (W_OUT * H_OUT)  // 262144

typedef float f4 __attribute__((ext_vector_type(4)));
typedef float f2 __attribute__((ext_vector_type(2)));

// Unaligned (4B-aligned) wide loads: row stride 513 floats makes 16B
// alignment impossible; gfx950 global loads support this in one dwordx4.
__device__ __forceinline__ f4 load4u(const float* p) {
    f4 v; __builtin_memcpy(&v, p, 16); return v;
}
__device__ __forceinline__ f2 load2u(const float* p) {
    f2 v; __builtin_memcpy(&v, p, 8); return v;
}

// One input row's 11-float window for 8 output cols: cols c-1 .. c+9.
struct Win { f4 a, b; f2 c2; float m1; };

__global__ __launch_bounds__(256)
void blur_kernel(const float* __restrict__ in,
                 const float* __restrict__ kern,
                 float* __restrict__ out)
{
    const int t    = threadIdx.x;
    const int lane = t & 63;
    const int wv   = t >> 6;           // wave index in block: 4 row strips
    const int c    = lane << 3;        // output col base 0..504 (64 lanes cover 512)
    const int cm1  = (c == 0) ? 0 : (c - 1);   // clamped addr for col c-1 (no OOB-before-plane)
    const int y0   = (blockIdx.x * 4 + wv) * 32;
    const int p    = blockIdx.y;       // plane (n*c), 512 total

    const float* __restrict__ ip = in + (size_t)p * IN_PLANE;
    float* __restrict__ op = out + (size_t)p * OUT_PLANE + (size_t)y0 * W_OUT + c;

    // Separable factors (identical derivation to baseline; kern is rank-1).
    const float kx0 = kern[2 * 4 + 3];   // wf[1][0]
    const float kx1 = kern[2 * 4 + 2];   // wf[1][1]
    const float kx2 = kern[2 * 4 + 1];   // wf[1][2]
    const float kx3 = kern[2 * 4 + 0];   // wf[1][3]
    const float inv = 1.0f / kx1;
    const float a0  = kern[3 * 4 + 2] * inv;   // vertical taps, a1 == 1
    const float a2  = kern[1 * 4 + 2] * inv;
    const float a3  = kern[0 * 4 + 2] * inv;

    // Column pad masks (thread-invariant): col -1 (left pad) and col 513 (right pad).
    const float mL = (c == 0)         ? 0.0f : 1.0f;   // masks W[0]
    const float mR = (c == W_OUT - 8) ? 0.0f : 1.0f;   // masks W[10] (col c+9==513)

    // Issue loads for input row ri (address-clamped; validity folded in at hcomp).
    auto ldrow = [&](int ri, Win& w) {
        const int riC = ri < 0 ? 0 : (ri > H_IN - 1 ? H_IN - 1 : ri);
        const float* rp = ip + (size_t)riC * W_IN;
        w.m1 = rp[cm1];              // col c-1
        w.a  = load4u(rp + c);       // cols c..c+3
        w.b  = load4u(rp + c + 4);   // cols c+4..c+7
        w.c2 = load2u(rp + c + 8);   // cols c+8,c+9 (worst case 4B past plane: page slack)
    };

    // Horizontal 4-tap: h[k] = FIR over cols c+k-1..c+k+2. Rows -1/513 (zero pad)
    // handled branchlessly by zeroing the row's coefficients (h linear in kx).
    auto hcomp = [&](int ri, const Win& w, float* h) {
        const float rv = (ri >= 0 && ri < H_IN) ? 1.0f : 0.0f;
        const float k0 = kx0 * rv, k1 = kx1 * rv, k2 = kx2 * rv, k3 = kx3 * rv;
        float W[11];
        W[0]  = w.m1 * mL;
        W[1]  = w.a.x; W[2] = w.a.y; W[3] = w.a.z; W[4] = w.a.w;
        W[5]  = w.b.x; W[6] = w.b.y; W[7] = w.b.z; W[8] = w.b.w;
        W[9]  = w.c2.x;
        W[10] = w.c2.y * mR;
#pragma unroll
        for (int k = 0; k < 8; ++k)
            h[k] = W[k] * k0 + W[k + 1] * k1 + W[k + 2] * k2 + W[k + 3] * k3;
    };

    // Vertical 4-tap (a1==1) + two aligned dwordx4 stores.
    auto vstore = [&](int r, const float* h0, const float* h1,
                      const float* h2, const float* h3) {
        float o[8];
#pragma unroll
        for (int k = 0; k < 8; ++k)
            o[k] = a0 * h0[k] + h1[k] + a2 * h2[k] + a3 * h3[k];
        *reinterpret_cast<f4*>(op + (size_t)r * W_OUT)     = (f4){o[0], o[1], o[2], o[3]};
        *reinterpret_cast<f4*>(op + (size_t)r * W_OUT + 4) = (f4){o[4], o[5], o[6], o[7]};
    };

    Win L0, L1, L2, L3;
    float hA[8], hB[8], hC[8], hD[8];

    // Prologue: 16 loads in flight before first compute.
    ldrow(y0 - 1, L0);
    ldrow(y0,     L1);
    ldrow(y0 + 1, L2);
    ldrow(y0 + 2, L3);
    hcomp(y0 - 1, L0, hA);
    hcomp(y0,     L1, hB);
    hcomp(y0 + 1, L2, hC);

    // Steady state: each step issues next row's loads, then consumes the
    // window loaded one step earlier (latency hidden under h/v compute).
    for (int r = 0; r < 32; r += 4) {
        ldrow(y0 + 3 + r, L0);
        hcomp(y0 + 2 + r, L3, hD);
        vstore(r,     hA, hB, hC, hD);

        ldrow(y0 + 4 + r, L1);
        hcomp(y0 + 3 + r, L0, hA);
        vstore(r + 1, hB, hC, hD, hA);

        ldrow(y0 + 5 + r, L2);
        hcomp(y0 + 4 + r, L1, hB);
        vstore(r + 2, hC, hD, hA, hB);

        ldrow(y0 + 6 + r, L3);
        hcomp(y0 + 5 + r, L2, hC);
        vstore(r + 3, hD, hA, hB, hC);
    }
}

extern "C" void kernel_launch(void* const* d_in, const int* in_sizes, int n_in,
                              void* d_out, int out_size, void* d_ws, size_t ws_size,
                              hipStream_t stream) {
    const float* x    = (const float*)d_in[0];  // (4,128,513,513) f32
    const float* kern = (const float*)d_in[1];  // (4,4) f32
    float* out        = (float*)d_out;          // (4,128,512,512) f32

    // Each block: 4 waves x (512 cols x 32 rows) = 512x128 of one plane.
    // Grid: 4 row-groups x 512 planes = 2048 blocks (8/CU exactly).
    dim3 grid(H_OUT / 128, 4 * 128, 1);
    dim3 block(256, 1, 1);
    blur_kernel<<<grid, block, 0, stream>>>(x, kern, out);
}